// Round 7
// baseline (28.144 us; speedup 1.0000x reference)
//
#include <hip/hip_runtime.h>

#define NB 4096
#define T_FRAMES 8192
#define T_TOKENS 2048
#define NTHREADS 512
#define TPT (T_TOKENS / NTHREADS)   // 4 tokens per thread
#define NWAVES (NTHREADS / 64)      // 8
#define MAX_DUR_M1 7                // durations in [0, 8)

__device__ __forceinline__ void load_lds16(const float4* g, float4* l) {
    __builtin_amdgcn_global_load_lds(
        (const __attribute__((address_space(1))) void*)g,
        (__attribute__((address_space(3))) void*)l,
        16, 0, 0);
}

__global__ __launch_bounds__(NTHREADS, 8) void avg_by_dur_kernel(
    const float* __restrict__ frame_scalar,
    const int*   __restrict__ frame_len,
    const int*   __restrict__ duration,
    const int*   __restrict__ duration_len,
    float*       __restrict__ out)
{
    __shared__ float s_frame[T_FRAMES];   // 32 KB, shared address space, per-wave spans
    __shared__ int   s_wsum[NWAVES];

    const int row  = blockIdx.x;
    const int t    = threadIdx.x;
    const int lane = t & 63;
    const int wid  = t >> 6;

    const int L    = frame_len[row];
    const int dlen = duration_len[row];

    // ---- output 1 early (independent of everything else)
    if (t == 0) {
        out[(size_t)NB * T_TOKENS + row] = (float)dlen;
    }

    // ---- durations for this thread's 4 tokens (one int4; skip if all >= dlen)
    int d[TPT] = {0, 0, 0, 0};
    if (t * TPT < dlen) {
        const int4 a = reinterpret_cast<const int4*>(duration + (size_t)row * T_TOKENS)[t];
        d[0] = a.x; d[1] = a.y; d[2] = a.z; d[3] = a.w;
    }
    int incl[TPT];
    int run = 0;
    #pragma unroll
    for (int k = 0; k < TPT; ++k) {
        int v = d[k] > 0 ? d[k] : 0;
        run += v;
        incl[k] = run;
    }

    // ---- wave-level inclusive scan of per-thread sums
    int x = run;
    #pragma unroll
    for (int off = 1; off < 64; off <<= 1) {
        int y = __shfl_up(x, off, 64);
        if (lane >= off) x += y;
    }
    if (lane == 63) s_wsum[wid] = x;

    // ---- the ONLY block-wide barrier: publish per-wave duration sums
    __syncthreads();

    int wbase = 0;
    #pragma unroll
    for (int w = 0; w < NWAVES; ++w)
        if (w < wid) wbase += s_wsum[w];
    const int wsum = s_wsum[wid];
    const int base = wbase + (x - run);   // exclusive prefix over all prior tokens

    // ---- this wave's exact frame span [rs, re); its threads read only this
    const int rs  = wbase < L ? wbase : L;
    const int re  = (wbase + wsum) < L ? (wbase + wsum) : L;
    const int rs4 = rs >> 2;
    const int n4  = ((re + 3) >> 2) - rs4;     // <= 449 float4

    // ---- per-wave async global->LDS staging at identity offsets.
    // Boundary float4s may be written by two waves with IDENTICAL data -> benign.
    const float4* g4 = reinterpret_cast<const float4*>(frame_scalar + (size_t)row * T_FRAMES) + rs4;
    float4* l4 = reinterpret_cast<float4*>(s_frame) + rs4;
    const int rounds = (n4 + 63) >> 6;         // wave-uniform
    for (int i = 0; i < rounds; ++i) {
        const int p = i * 64 + lane;
        if (p < n4) load_lds16(g4 + p, l4 + p);
    }
    // Wait only THIS wave's staging loads; no block-wide rendezvous.
    asm volatile("s_waitcnt vmcnt(0)" ::: "memory");

    // ---- per-token segment means from LDS
    float outv[TPT];
    int start = base < L ? base : L;
    #pragma unroll
    for (int k = 0; k < TPT; ++k) {
        int e = base + incl[k];
        if (e > L) e = L;
        const int j = t * TPT + k;
        const int len = e - start;
        float r = 0.0f;
        if (len > 0 && j < dlen) {
            float s = 0.0f;
            #pragma unroll
            for (int q = 0; q < MAX_DUR_M1; ++q) {
                const int idx = start + q;
                const float v = s_frame[idx < e ? idx : start];
                if (idx < e) s += v;
            }
            r = s / (float)len;
        }
        outv[k] = r;
        start = e;
    }

    // ---- coalesced store: one float4 per thread
    reinterpret_cast<float4*>(out + (size_t)row * T_TOKENS)[t] =
        make_float4(outv[0], outv[1], outv[2], outv[3]);
}

extern "C" void kernel_launch(void* const* d_in, const int* in_sizes, int n_in,
                              void* d_out, int out_size, void* d_ws, size_t ws_size,
                              hipStream_t stream) {
    const float* frame_scalar     = (const float*)d_in[0];
    const int*   frame_scalar_len = (const int*)d_in[1];
    const int*   duration         = (const int*)d_in[2];
    const int*   duration_len     = (const int*)d_in[3];
    float* out = (float*)d_out;

    avg_by_dur_kernel<<<NB, NTHREADS, 0, stream>>>(
        frame_scalar, frame_scalar_len, duration, duration_len, out);
}